// Round 2
// baseline (450.292 us; speedup 1.0000x reference)
//
#include <hip/hip_runtime.h>
#include <stdint.h>

#define BATCH 32
#define CIN   128
#define HH    56
#define WW    56
#define COUT  256
#define HP    58
#define WP    58

typedef __attribute__((ext_vector_type(8))) short short8;
typedef __attribute__((ext_vector_type(4))) float floatx4;

__device__ __forceinline__ unsigned short f32_to_bf16(float f) {
  unsigned int u = __float_as_uint(f);
  u = u + 0x7fffu + ((u >> 16) & 1u);
  return (unsigned short)(u >> 16);
}

// ws layout: [xp_t: BATCH*HP*WP*CIN bf16][slack 1024][wt: 9*COUT*CIN bf16]
// xp_t NHWC padded: xp_t[((b*58+i)*58+j)*128+ci] = x[b][ci][i-1][j-1] or 0.
// A-tile reads may overrun a row by <= 8 cols (w>=56 garbage rows, discarded);
// max overrun past the last row is exactly 1024 elems -> SLACK covers it.

__global__ void pad_transpose_kernel(const float* __restrict__ x,
                                     unsigned short* __restrict__ xpt) {
  __shared__ float tile[CIN * 59];
  const int blk = blockIdx.x;  // b*58 + i
  const int b = blk / HP;
  const int i = blk - b * HP;
  const int t = threadIdx.x;
  for (int e = t; e < CIN * 59; e += 256) tile[e] = 0.0f;
  __syncthreads();
  if (i >= 1 && i <= HH) {
    for (int e = t; e < CIN * WW; e += 256) {
      int ci = e / WW;
      int w = e - ci * WW;
      tile[ci * 59 + w + 1] =
          x[(((size_t)b * CIN + ci) * HH + (i - 1)) * WW + w];
    }
  }
  __syncthreads();
  unsigned short* dst = xpt + (size_t)blk * (WP * CIN);
  for (int e = t; e < WP * CIN; e += 256) {
    int j = e >> 7;
    int ci = e & 127;
    dst[e] = f32_to_bf16(tile[ci * 59 + j]);
  }
}

__global__ void weight_transpose_kernel(const float* __restrict__ wsrc,
                                        unsigned short* __restrict__ wt) {
  int o = blockIdx.x * 256 + threadIdx.x;
  int ci = o & 127;
  int co = (o >> 7) & 255;
  int r = o >> 15;
  wt[o] = f32_to_bf16(wsrc[((size_t)co * CIN + ci) * 9 + r]);
}

// 128x128 block tile, BK=32, 4 waves 2x2, 64x64/wave, software-pipelined:
// global->reg prefetch of stage s+1 issued before stage s's MFMAs.
// Epilogue round-trips through LDS so global stores are dense 224B rows.
__global__ __launch_bounds__(256, 4) void conv_gemm_kernel(
    const unsigned short* __restrict__ xpt,
    const unsigned short* __restrict__ wt,
    const float* __restrict__ bias,
    float* __restrict__ out) {
  __shared__ __align__(16) uint32_t smem[5120];  // 20480 B
  short* As = (short*)smem;                 // [128][40] shorts
  short* Bs = ((short*)smem) + 128 * 40;    // [128][40] shorts
  float* ep = (float*)smem;                 // [32][132] floats (epilogue)

  const int nt = blockIdx.x & 1;
  const int mt = blockIdx.x >> 1;  // 0..895
  const int b = mt / 28;
  const int h0 = (mt - b * 28) * 2;
  const int co0 = nt * 128;

  const int t = threadIdx.x;
  const int lane = t & 63;
  const int wv = t >> 6;
  const int mw = wv & 1;
  const int nw = wv >> 1;
  const int laneM = lane & 15;
  const int laneK = (lane >> 4) * 8;
  const int rowreg = (lane >> 4) * 4;

  // staging thread->element mapping (two chunks per array)
  const int mm0 = t >> 2;              // 0..63
  const int j80 = (t & 3) * 8;
  const int mm1 = (t + 256) >> 2;      // 64..127
  const int j81 = j80;                 // (t+256)&3 == t&3

  floatx4 acc[4][4] = {};
  uint4 aval[2], bval[2];

  auto load_stage = [&](int s) {
    const int r = s >> 2;
    const int kt = s & 3;
    const int dh = (r * 11) >> 5;  // r/3 for r in [0,8]
    const int dw = r - dh * 3;
    const int ci0 = kt * 32;
    {
      const int hp = h0 + (mm0 >> 6) + dh;
      const int wc = (mm0 & 63) + dw;
      aval[0] = *(const uint4*)(xpt +
          ((size_t)((b * HP + hp) * WP + wc)) * CIN + ci0 + j80);
      bval[0] = *(const uint4*)(wt + (size_t)r * (COUT * CIN) +
          (size_t)(co0 + mm0) * CIN + ci0 + j80);
    }
    {
      const int hp = h0 + (mm1 >> 6) + dh;
      const int wc = (mm1 & 63) + dw;
      aval[1] = *(const uint4*)(xpt +
          ((size_t)((b * HP + hp) * WP + wc)) * CIN + ci0 + j81);
      bval[1] = *(const uint4*)(wt + (size_t)r * (COUT * CIN) +
          (size_t)(co0 + mm1) * CIN + ci0 + j81);
    }
  };

  load_stage(0);

  for (int s = 0; s < 36; ++s) {
    __syncthreads();  // previous stage's frag reads done
    *(uint4*)&As[mm0 * 40 + j80] = aval[0];
    *(uint4*)&As[mm1 * 40 + j81] = aval[1];
    *(uint4*)&Bs[mm0 * 40 + j80] = bval[0];
    *(uint4*)&Bs[mm1 * 40 + j81] = bval[1];
    __syncthreads();
    if (s + 1 < 36) load_stage(s + 1);  // prefetch: latency hidden by MFMAs

    short8 af[4], bfr[4];
#pragma unroll
    for (int mi = 0; mi < 4; ++mi)
      af[mi] = *(const short8*)&As[(mw * 64 + mi * 16 + laneM) * 40 + laneK];
#pragma unroll
    for (int ni = 0; ni < 4; ++ni)
      bfr[ni] = *(const short8*)&Bs[(nw * 64 + ni * 16 + laneM) * 40 + laneK];
#pragma unroll
    for (int mi = 0; mi < 4; ++mi)
#pragma unroll
      for (int ni = 0; ni < 4; ++ni)
        acc[mi][ni] = __builtin_amdgcn_mfma_f32_16x16x32_bf16(
            af[mi], bfr[ni], acc[mi][ni], 0, 0, 0);
  }

  // Epilogue: 4 chunks of 32co x 128m through LDS -> dense 224B row stores.
  // acc[mi][ni] lane l: m = mw*64+mi*16+(l>>4)*4+reg, co = co0+nw*64+ni*16+(l&15)
  for (int ni = 0; ni < 4; ++ni) {
    __syncthreads();  // LDS free
#pragma unroll
    for (int mi = 0; mi < 4; ++mi) {
      *(float4*)&ep[(nw * 16 + laneM) * 132 + mw * 64 + mi * 16 + rowreg] =
          *(float4*)&acc[mi][ni];
    }
    __syncthreads();
#pragma unroll
    for (int rr = 0; rr < 16; ++rr) {
      const int rowid = wv * 16 + rr;
      const int cg = rowid >> 1;   // 0..31
      const int hh = rowid & 1;
      const int co = co0 + (cg >> 4) * 64 + ni * 16 + (cg & 15);
      const float bv = bias[co];
      if (lane < WW) {
        const float v = ep[cg * 132 + hh * 64 + lane] + bv;
        out[(((size_t)b * COUT + co) * HH + h0 + hh) * WW + lane] = v;
      }
    }
  }
}

// Fallback if ws is too small: correct but slow.
__global__ void naive_conv_kernel(const float* __restrict__ x,
                                  const float* __restrict__ wgt,
                                  const float* __restrict__ bias,
                                  float* __restrict__ out, long n) {
  long idx = (long)blockIdx.x * 256 + threadIdx.x;
  if (idx >= n) return;
  int w = (int)(idx % WW);
  long q = idx / WW;
  int h = (int)(q % HH);
  q /= HH;
  int co = (int)(q % COUT);
  int b = (int)(q / COUT);
  float s = bias[co];
  for (int ci = 0; ci < CIN; ++ci) {
    const float* xp = x + (((size_t)b * CIN + ci) * HH) * WW;
    const float* wp = wgt + ((size_t)co * CIN + ci) * 9;
    for (int dh = 0; dh < 3; ++dh) {
      int hh = h + dh - 1;
      if (hh < 0 || hh >= HH) continue;
      for (int dw = 0; dw < 3; ++dw) {
        int ww2 = w + dw - 1;
        if (ww2 < 0 || ww2 >= WW) continue;
        s += xp[hh * WW + ww2] * wp[dh * 3 + dw];
      }
    }
  }
  out[idx] = s;
}

extern "C" void kernel_launch(void* const* d_in, const int* in_sizes, int n_in,
                              void* d_out, int out_size, void* d_ws,
                              size_t ws_size, hipStream_t stream) {
  const float* x = (const float*)d_in[0];
  const float* wgt = (const float*)d_in[1];
  const float* bias = (const float*)d_in[2];
  float* out = (float*)d_out;

  const size_t XPT = (size_t)BATCH * HP * WP * CIN;  // 13,778,944
  const size_t SLACK = 1024;
  const size_t WT = (size_t)9 * COUT * CIN;  // 294,912
  const size_t need = (XPT + SLACK + WT) * sizeof(unsigned short);

  if (ws_size >= need) {
    unsigned short* xpt = (unsigned short*)d_ws;
    unsigned short* wtp = xpt + XPT + SLACK;
    hipLaunchKernelGGL(pad_transpose_kernel, dim3(BATCH * HP), dim3(256), 0,
                       stream, x, xpt);
    hipLaunchKernelGGL(weight_transpose_kernel, dim3((9 * COUT * CIN) / 256),
                       dim3(256), 0, stream, wgt, wtp);
    hipLaunchKernelGGL(conv_gemm_kernel, dim3(896 * 2), dim3(256), 0, stream,
                       xpt, wtp, bias, out);
  } else {
    long n = (long)out_size;
    hipLaunchKernelGGL(naive_conv_kernel, dim3((unsigned)((n + 255) / 256)),
                       dim3(256), 0, stream, x, wgt, bias, out, n);
  }
}

// Round 3
// 245.175 us; speedup vs baseline: 1.8366x; 1.8366x over previous
//
#include <hip/hip_runtime.h>
#include <stdint.h>

#define BATCH 32
#define CIN   128
#define HH    56
#define WW    56
#define COUT  256
#define HP    58
#define WP    58

typedef __attribute__((ext_vector_type(8))) short short8;
typedef __attribute__((ext_vector_type(4))) float floatx4;

// async global->LDS, 16B per lane; LDS dest = wave-uniform base + lane*16
#define GLOAD_LDS16(gptr, lptr)                                          \
  __builtin_amdgcn_global_load_lds(                                      \
      (const __attribute__((address_space(1))) void*)(gptr),             \
      (__attribute__((address_space(3))) void*)(lptr), 16, 0, 0)

__device__ __forceinline__ unsigned short f32_to_bf16(float f) {
  unsigned int u = __float_as_uint(f);
  u = u + 0x7fffu + ((u >> 16) & 1u);
  return (unsigned short)(u >> 16);
}
__device__ __forceinline__ unsigned int pack2(float a, float b) {
  return (unsigned int)f32_to_bf16(a) | ((unsigned int)f32_to_bf16(b) << 16);
}

// ws layout: [xp_t: BATCH*HP*WP*CIN bf16][slack 1024][wt: 9*COUT*CIN bf16]
// xp_t NHWC padded: xp_t[((b*58+i)*58+j)*128+ci] = x[b][ci][i-1][j-1] or 0.
// A-tile reads may overrun a row by <= 9 cols; those rows (w>=56) are
// discarded in the epilogue; max overrun past the array end = 1024 elems
// (covered by SLACK, values finite bf16 garbage).

__global__ void pad_transpose_kernel(const float* __restrict__ x,
                                     unsigned short* __restrict__ xpt) {
  __shared__ float tile[CIN * 59];  // [ci][59], stride 59 breaks pow2 banks
  const int blk = blockIdx.x;       // b*58 + i
  const int b = blk / HP;
  const int i = blk - b * HP;
  const int t = threadIdx.x;
  for (int e = t; e < CIN * 59; e += 256) tile[e] = 0.0f;
  __syncthreads();
  if (i >= 1 && i <= HH) {
    const float* src = x + ((size_t)b * CIN * HH + (i - 1)) * WW;
    for (int e = t; e < CIN * WW; e += 256) {
      int ci = e / WW;
      int w = e - ci * WW;
      tile[ci * 59 + w + 1] = src[(size_t)ci * (HH * WW) + w];
    }
  }
  __syncthreads();
  // dst[j*128 + ci], 928 uint4s; uint4 idx -> j = idx>>4, ci0 = (idx&15)*8
  unsigned short* dst = xpt + (size_t)blk * (WP * CIN);
  for (int idx = t; idx < 928; idx += 256) {
    const int j = idx >> 4;
    const int ci0 = (idx & 15) * 8;
    uint4 pk;
    pk.x = pack2(tile[(ci0 + 0) * 59 + j], tile[(ci0 + 1) * 59 + j]);
    pk.y = pack2(tile[(ci0 + 2) * 59 + j], tile[(ci0 + 3) * 59 + j]);
    pk.z = pack2(tile[(ci0 + 4) * 59 + j], tile[(ci0 + 5) * 59 + j]);
    pk.w = pack2(tile[(ci0 + 6) * 59 + j], tile[(ci0 + 7) * 59 + j]);
    *(uint4*)(dst + (size_t)idx * 8) = pk;
  }
}

// wt[r][co][ci] = weight[co][ci][r], bf16. 36864 uint4s, 144 blocks.
__global__ void weight_transpose_kernel(const float* __restrict__ wsrc,
                                        unsigned short* __restrict__ wt) {
  const int o8 = blockIdx.x * 256 + threadIdx.x;  // uint4 index
  const int r = o8 >> 12;
  const int rem = o8 & 4095;
  const int co = rem >> 4;
  const int ci0 = (rem & 15) * 8;
  const float* s = wsrc + ((size_t)co * CIN + ci0) * 9 + r;
  uint4 pk;
  pk.x = pack2(s[0 * 9], s[1 * 9]);
  pk.y = pack2(s[2 * 9], s[3 * 9]);
  pk.z = pack2(s[4 * 9], s[5 * 9]);
  pk.w = pack2(s[6 * 9], s[7 * 9]);
  *(uint4*)(wt + (size_t)o8 * 8) = pk;
}

// 128x128 block tile, BK=32, 4 waves 2x2, 64x64/wave; m97-style staging:
// global_load_lds dwordx4 into unpadded [128][32] LDS tiles, vmcnt drained
// at the barrier. Epilogue round-trips LDS -> dense 224B row stores.
__global__ __launch_bounds__(256) void conv_gemm_kernel(
    const unsigned short* __restrict__ xpt,
    const unsigned short* __restrict__ wt,
    const float* __restrict__ bias,
    float* __restrict__ out) {
  __shared__ __align__(16) uint32_t smem[4224];  // 16896 B
  short* As = (short*)smem;             // [128][32] shorts, 8192 B
  short* Bs = (short*)smem + 4096;      // [128][32] shorts, 8192 B
  float* ep = (float*)smem;             // [32][132] floats (epilogue alias)

  const int nt = blockIdx.x & 1;
  const int mt = blockIdx.x >> 1;  // 0..895
  const int b = mt / 28;
  const int h0 = (mt - b * 28) * 2;
  const int co0 = nt * 128;

  const int t = threadIdx.x;
  const int lane = t & 63;
  const int wv = t >> 6;
  const int mw = wv & 1;
  const int nw = wv >> 1;
  const int laneM = lane & 15;
  const int laneK = (lane >> 4) * 8;
  const int rowreg = (lane >> 4) * 4;

  // staging bases: chunk c covers u = c*256 + t; mm = u>>2 (tile row),
  // j8 = (u&3)*8 (k element). LDS byte addr = u*16 = wave-uniform + lane*16.
  const unsigned short* ag[2];
  const unsigned short* bg[2];
  short* al[2];
  short* bl[2];
#pragma unroll
  for (int c = 0; c < 2; ++c) {
    const int u = c * 256 + t;
    const int mm = u >> 2;
    const int j8 = (u & 3) * 8;
    const int hp0 = h0 + (mm >> 6);   // + dh later
    const int wc0 = mm & 63;          // + dw later
    ag[c] = xpt + ((size_t)((b * HP + hp0) * WP + wc0)) * CIN + j8;
    bg[c] = wt + (size_t)(co0 + mm) * CIN + j8;
    const int ub = (c * 256 + wv * 64) * 8;  // wave-uniform elem offset
    al[c] = As + ub;
    bl[c] = Bs + ub;
  }

  floatx4 acc[4][4] = {};

  for (int r = 0; r < 9; ++r) {
    const int dh = (r * 11) >> 5;  // r/3
    const int dw = r - dh * 3;
    const int aoff = (dh * WP + dw) * CIN;
    const int boff = r * (COUT * CIN);
#pragma unroll
    for (int kt = 0; kt < 4; ++kt) {
      const int ci0 = kt * 32;
      GLOAD_LDS16(ag[0] + aoff + ci0, al[0]);
      GLOAD_LDS16(ag[1] + aoff + ci0, al[1]);
      GLOAD_LDS16(bg[0] + boff + ci0, bl[0]);
      GLOAD_LDS16(bg[1] + boff + ci0, bl[1]);
      __syncthreads();  // drains vmcnt(0): tile visible in LDS

      short8 af[4], bfr[4];
#pragma unroll
      for (int mi = 0; mi < 4; ++mi)
        af[mi] = *(const short8*)&As[(mw * 64 + mi * 16 + laneM) * 32 + laneK];
#pragma unroll
      for (int ni = 0; ni < 4; ++ni)
        bfr[ni] = *(const short8*)&Bs[(nw * 64 + ni * 16 + laneM) * 32 + laneK];
#pragma unroll
      for (int mi = 0; mi < 4; ++mi)
#pragma unroll
        for (int ni = 0; ni < 4; ++ni)
          acc[mi][ni] = __builtin_amdgcn_mfma_f32_16x16x32_bf16(
              af[mi], bfr[ni], acc[mi][ni], 0, 0, 0);
      __syncthreads();  // readers done before next stage overwrites
    }
  }

  // Epilogue: 4 chunks of 32co x 128m via LDS -> dense 224B row stores.
  // acc[mi][ni] lane l: m = mw*64+mi*16+(l>>4)*4+reg, co = co0+nw*64+ni*16+(l&15)
  for (int ni = 0; ni < 4; ++ni) {
    __syncthreads();
#pragma unroll
    for (int mi = 0; mi < 4; ++mi)
      *(float4*)&ep[(nw * 16 + laneM) * 132 + mw * 64 + mi * 16 + rowreg] =
          *(float4*)&acc[mi][ni];
    __syncthreads();
#pragma unroll
    for (int rr = 0; rr < 16; ++rr) {
      const int rowid = wv * 16 + rr;
      const int cg = rowid >> 1;  // 0..31: (nw<<4)|laneM of producer
      const int hh = rowid & 1;
      const int co = co0 + (cg >> 4) * 64 + ni * 16 + (cg & 15);
      const float bv = bias[co];
      if (lane < WW) {
        out[(((size_t)b * COUT + co) * HH + h0 + hh) * WW + lane] =
            ep[cg * 132 + hh * 64 + lane] + bv;
      }
    }
  }
}

// Fallback if ws is too small: correct but slow.
__global__ void naive_conv_kernel(const float* __restrict__ x,
                                  const float* __restrict__ wgt,
                                  const float* __restrict__ bias,
                                  float* __restrict__ out, long n) {
  long idx = (long)blockIdx.x * 256 + threadIdx.x;
  if (idx >= n) return;
  int w = (int)(idx % WW);
  long q = idx / WW;
  int h = (int)(q % HH);
  q /= HH;
  int co = (int)(q % COUT);
  int b = (int)(q / COUT);
  float s = bias[co];
  for (int ci = 0; ci < CIN; ++ci) {
    const float* xp = x + (((size_t)b * CIN + ci) * HH) * WW;
    const float* wp = wgt + ((size_t)co * CIN + ci) * 9;
    for (int dh = 0; dh < 3; ++dh) {
      int hh = h + dh - 1;
      if (hh < 0 || hh >= HH) continue;
      for (int dw = 0; dw < 3; ++dw) {
        int ww2 = w + dw - 1;
        if (ww2 < 0 || ww2 >= WW) continue;
        s += xp[hh * WW + ww2] * wp[dh * 3 + dw];
      }
    }
  }
  out[idx] = s;
}

extern "C" void kernel_launch(void* const* d_in, const int* in_sizes, int n_in,
                              void* d_out, int out_size, void* d_ws,
                              size_t ws_size, hipStream_t stream) {
  const float* x = (const float*)d_in[0];
  const float* wgt = (const float*)d_in[1];
  const float* bias = (const float*)d_in[2];
  float* out = (float*)d_out;

  const size_t XPT = (size_t)BATCH * HP * WP * CIN;  // 13,778,944
  const size_t SLACK = 1024;
  const size_t WT = (size_t)9 * COUT * CIN;  // 294,912
  const size_t need = (XPT + SLACK + WT) * sizeof(unsigned short);

  if (ws_size >= need) {
    unsigned short* xpt = (unsigned short*)d_ws;
    unsigned short* wtp = xpt + XPT + SLACK;
    hipLaunchKernelGGL(pad_transpose_kernel, dim3(BATCH * HP), dim3(256), 0,
                       stream, x, xpt);
    hipLaunchKernelGGL(weight_transpose_kernel, dim3(144), dim3(256), 0,
                       stream, wgt, wtp);
    hipLaunchKernelGGL(conv_gemm_kernel, dim3(896 * 2), dim3(256), 0, stream,
                       xpt, wtp, bias, out);
  } else {
    long n = (long)out_size;
    hipLaunchKernelGGL(naive_conv_kernel, dim3((unsigned)((n + 255) / 256)),
                       dim3(256), 0, stream, x, wgt, bias, out, n);
  }
}

// Round 4
// 216.946 us; speedup vs baseline: 2.0756x; 1.1301x over previous
//
#include <hip/hip_runtime.h>
#include <stdint.h>

#define BATCH 32
#define CIN   128
#define HH    56
#define WW    56
#define COUT  256
#define HP    58
#define WP    58

typedef __attribute__((ext_vector_type(8))) short short8;
typedef __attribute__((ext_vector_type(4))) float floatx4;

// async global->LDS, 16B per lane; LDS dest = wave-uniform base + lane*16
#define GLOAD_LDS16(gptr, lptr)                                          \
  __builtin_amdgcn_global_load_lds(                                      \
      (const __attribute__((address_space(1))) void*)(gptr),             \
      (__attribute__((address_space(3))) void*)(lptr), 16, 0, 0)

__device__ __forceinline__ unsigned short f32_to_bf16(float f) {
  unsigned int u = __float_as_uint(f);
  u = u + 0x7fffu + ((u >> 16) & 1u);
  return (unsigned short)(u >> 16);
}
__device__ __forceinline__ unsigned int pack2(float a, float b) {
  return (unsigned int)f32_to_bf16(a) | ((unsigned int)f32_to_bf16(b) << 16);
}

// ws layout: [xp_t: BATCH*HP*WP*CIN bf16][slack 1024][wt: 9*COUT*CIN bf16]
// xp_t NHWC padded: xp_t[((b*58+i)*58+j)*128+ci] = x[b][ci][i-1][j-1] or 0.
// GEMM A-reads may overrun a row by <= 9 cols (rows w>=56 discarded in the
// epilogue); max overrun past the array end is < 1024 elems (SLACK).

__global__ void pad_transpose_kernel(const float* __restrict__ x,
                                     unsigned short* __restrict__ xpt) {
  const int blk = blockIdx.x;  // b*58 + i
  const int b = blk / HP;
  const int i = blk - b * HP;
  const int t = threadIdx.x;
  unsigned short* dst = xpt + (size_t)blk * (WP * CIN);

  if (i == 0 || i == HP - 1) {  // pure pad row: store zeros, no LDS
    const uint4 z = {0, 0, 0, 0};
    for (int idx = t; idx < 928; idx += 256)
      *(uint4*)(dst + (size_t)idx * 8) = z;
    return;
  }

  __shared__ float tile[CIN * 59];  // [ci][0..57]; col0/col57 = pad
  // zero the two pad columns only
  tile[(t >> 1) * 59 + (t & 1) * 57] = 0.0f;
  // float4 row loads: ci = t>>1, seg = t&1 covers w = seg*28 .. seg*28+27
  {
    const int ci = t >> 1;
    const int seg = t & 1;
    const float* row =
        x + (((size_t)b * CIN + ci) * HH + (i - 1)) * WW + seg * 28;
    float* trow = tile + ci * 59 + 1 + seg * 28;
#pragma unroll
    for (int q = 0; q < 7; ++q) {
      const float4 v = *(const float4*)(row + q * 4);
      trow[q * 4 + 0] = v.x;
      trow[q * 4 + 1] = v.y;
      trow[q * 4 + 2] = v.z;
      trow[q * 4 + 3] = v.w;
    }
  }
  __syncthreads();
  // pack: dst[j*128 + ci] bf16; idx -> j = idx>>4, ci0 = (idx&15)*8
  for (int idx = t; idx < 928; idx += 256) {
    const int j = idx >> 4;
    const int ci0 = (idx & 15) * 8;
    uint4 pk;
    pk.x = pack2(tile[(ci0 + 0) * 59 + j], tile[(ci0 + 1) * 59 + j]);
    pk.y = pack2(tile[(ci0 + 2) * 59 + j], tile[(ci0 + 3) * 59 + j]);
    pk.z = pack2(tile[(ci0 + 4) * 59 + j], tile[(ci0 + 5) * 59 + j]);
    pk.w = pack2(tile[(ci0 + 6) * 59 + j], tile[(ci0 + 7) * 59 + j]);
    *(uint4*)(dst + (size_t)idx * 8) = pk;
  }
}

// wt[r][co][ci] = weight[co][ci][r], bf16. 36864 uint4s, 144 blocks.
__global__ void weight_transpose_kernel(const float* __restrict__ wsrc,
                                        unsigned short* __restrict__ wt) {
  const int o8 = blockIdx.x * 256 + threadIdx.x;
  const int r = o8 >> 12;
  const int rem = o8 & 4095;
  const int co = rem >> 4;
  const int ci0 = (rem & 15) * 8;
  const float* s = wsrc + ((size_t)co * CIN + ci0) * 9 + r;
  uint4 pk;
  pk.x = pack2(s[0 * 9], s[1 * 9]);
  pk.y = pack2(s[2 * 9], s[3 * 9]);
  pk.z = pack2(s[4 * 9], s[5 * 9]);
  pk.w = pack2(s[6 * 9], s[7 * 9]);
  *(uint4*)(wt + (size_t)o8 * 8) = pk;
}

// 128x128 tile, K=64 per barrier pair (two [128][32] sub-buffers per side),
// 4 waves 2x2, 64x64/wave. global_load_lds staging with XOR bank swizzle:
// 16B chunk p of LDS row mm holds global k-chunk (p ^ (mm&3)); frag reads
// apply the same XOR. XCD swizzle pairs nt-variants of one mt on one XCD.
__global__ __launch_bounds__(256) void conv_gemm_kernel(
    const unsigned short* __restrict__ xpt,
    const unsigned short* __restrict__ wt,
    const float* __restrict__ bias,
    float* __restrict__ out) {
  __shared__ __align__(16) uint32_t smem[8192];  // 32 KB
  short* const S = (short*)smem;
  short* const As0 = S;             // [128][32]
  short* const As1 = S + 4096;
  short* const Bs0 = S + 8192;
  short* const Bs1 = S + 12288;
  float* const ep = (float*)smem;   // epilogue alias [32][132]

  const int g = blockIdx.x;
  const int xcd = g & 7;
  const int jj = g >> 3;
  const int nt = jj & 1;
  const int mt = (jj >> 1) * 8 + xcd;  // 0..895, nt-pairs 8 apart (same XCD)
  const int b = mt / 28;
  const int h0 = (mt - b * 28) * 2;
  const int co0 = nt * 128;

  const int t = threadIdx.x;
  const int lane = t & 63;
  const int wv = t >> 6;
  const int mw = wv & 1;
  const int nw = wv >> 1;
  const int laneM = lane & 15;
  const int laneKg = lane >> 4;          // 0..3 (k-chunk group)
  const int xk = (laneKg ^ (laneM & 3)) * 8;  // XOR-swizzled frag k offset
  const int rowreg = laneKg * 4;

  // staging: per sub-buffer u = c*256 + t; mm = u>>2; p = u&3;
  // global k-chunk j8 = (p ^ (mm&3))*8; LDS chunk addr = u*16 B.
  const unsigned short* ag[2];
  const unsigned short* bg[2];
  short* al[2];
  short* bl[2];
#pragma unroll
  for (int c = 0; c < 2; ++c) {
    const int u = c * 256 + t;
    const int mm = u >> 2;
    const int j8 = (((u & 3) ^ (mm & 3)) * 8);
    const int hp0 = h0 + (mm >> 6);  // + dh later
    const int wc0 = mm & 63;         // + dw later
    ag[c] = xpt + ((size_t)((b * HP + hp0) * WP + wc0)) * CIN + j8;
    bg[c] = wt + (size_t)(co0 + mm) * CIN + j8;
    al[c] = As0 + (size_t)(c * 256 + wv * 64) * 8;
    bl[c] = Bs0 + (size_t)(c * 256 + wv * 64) * 8;
  }

  floatx4 acc[4][4] = {};

  for (int r = 0; r < 9; ++r) {
    const int dh = (r * 11) >> 5;  // r/3
    const int dw = r - dh * 3;
    const int aoff = (dh * WP + dw) * CIN;
    const int boff = r * (COUT * CIN);
#pragma unroll
    for (int kt = 0; kt < 2; ++kt) {
      const int ci0 = kt * 64;
      GLOAD_LDS16(ag[0] + aoff + ci0, al[0]);
      GLOAD_LDS16(ag[1] + aoff + ci0, al[1]);
      GLOAD_LDS16(ag[0] + aoff + ci0 + 32, al[0] + 4096);
      GLOAD_LDS16(ag[1] + aoff + ci0 + 32, al[1] + 4096);
      GLOAD_LDS16(bg[0] + boff + ci0, bl[0]);
      GLOAD_LDS16(bg[1] + boff + ci0, bl[1]);
      GLOAD_LDS16(bg[0] + boff + ci0 + 32, bl[0] + 4096);
      GLOAD_LDS16(bg[1] + boff + ci0 + 32, bl[1] + 4096);
      __syncthreads();  // drains vmcnt: both K=32 halves visible

#pragma unroll
      for (int half = 0; half < 2; ++half) {
        const short* Ah = half ? As1 : As0;
        const short* Bh = half ? Bs1 : Bs0;
        short8 af[4], bfr[4];
#pragma unroll
        for (int mi = 0; mi < 4; ++mi)
          af[mi] = *(const short8*)&Ah[(mw * 64 + mi * 16 + laneM) * 32 + xk];
#pragma unroll
        for (int ni = 0; ni < 4; ++ni)
          bfr[ni] = *(const short8*)&Bh[(nw * 64 + ni * 16 + laneM) * 32 + xk];
#pragma unroll
        for (int mi = 0; mi < 4; ++mi)
#pragma unroll
          for (int ni = 0; ni < 4; ++ni)
            acc[mi][ni] = __builtin_amdgcn_mfma_f32_16x16x32_bf16(
                af[mi], bfr[ni], acc[mi][ni], 0, 0, 0);
      }
      __syncthreads();  // readers done before next stage overwrites
    }
  }

  // Epilogue: 4 chunks of 32co x 128m via LDS -> dense 224B row stores.
  // acc[mi][ni] lane l: m = mw*64+mi*16+(l>>4)*4+reg, co = co0+nw*64+ni*16+(l&15)
  for (int ni = 0; ni < 4; ++ni) {
    __syncthreads();
#pragma unroll
    for (int mi = 0; mi < 4; ++mi)
      *(float4*)&ep[(nw * 16 + laneM) * 132 + mw * 64 + mi * 16 + rowreg] =
          *(float4*)&acc[mi][ni];
    __syncthreads();
#pragma unroll
    for (int rr = 0; rr < 16; ++rr) {
      const int rowid = wv * 16 + rr;
      const int cg = rowid >> 1;  // 0..31: (nw<<4)|laneM of producer
      const int hh = rowid & 1;
      const int co = co0 + (cg >> 4) * 64 + ni * 16 + (cg & 15);
      const float bv = bias[co];
      if (lane < WW) {
        out[(((size_t)b * COUT + co) * HH + h0 + hh) * WW + lane] =
            ep[cg * 132 + hh * 64 + lane] + bv;
      }
    }
  }
}

// Fallback if ws is too small: correct but slow.
__global__ void naive_conv_kernel(const float* __restrict__ x,
                                  const float* __restrict__ wgt,
                                  const float* __restrict__ bias,
                                  float* __restrict__ out, long n) {
  long idx = (long)blockIdx.x * 256 + threadIdx.x;
  if (idx >= n) return;
  int w = (int)(idx % WW);
  long q = idx / WW;
  int h = (int)(q % HH);
  q /= HH;
  int co = (int)(q % COUT);
  int b = (int)(q / COUT);
  float s = bias[co];
  for (int ci = 0; ci < CIN; ++ci) {
    const float* xp = x + (((size_t)b * CIN + ci) * HH) * WW;
    const float* wp = wgt + ((size_t)co * CIN + ci) * 9;
    for (int dh = 0; dh < 3; ++dh) {
      int hh = h + dh - 1;
      if (hh < 0 || hh >= HH) continue;
      for (int dw = 0; dw < 3; ++dw) {
        int ww2 = w + dw - 1;
        if (ww2 < 0 || ww2 >= WW) continue;
        s += xp[hh * WW + ww2] * wp[dh * 3 + dw];
      }
    }
  }
  out[idx] = s;
}

extern "C" void kernel_launch(void* const* d_in, const int* in_sizes, int n_in,
                              void* d_out, int out_size, void* d_ws,
                              size_t ws_size, hipStream_t stream) {
  const float* x = (const float*)d_in[0];
  const float* wgt = (const float*)d_in[1];
  const float* bias = (const float*)d_in[2];
  float* out = (float*)d_out;

  const size_t XPT = (size_t)BATCH * HP * WP * CIN;  // 13,778,944
  const size_t SLACK = 1024;
  const size_t WT = (size_t)9 * COUT * CIN;  // 294,912
  const size_t need = (XPT + SLACK + WT) * sizeof(unsigned short);

  if (ws_size >= need) {
    unsigned short* xpt = (unsigned short*)d_ws;
    unsigned short* wtp = xpt + XPT + SLACK;
    hipLaunchKernelGGL(pad_transpose_kernel, dim3(BATCH * HP), dim3(256), 0,
                       stream, x, xpt);
    hipLaunchKernelGGL(weight_transpose_kernel, dim3(144), dim3(256), 0,
                       stream, wgt, wtp);
    hipLaunchKernelGGL(conv_gemm_kernel, dim3(896 * 2), dim3(256), 0, stream,
                       xpt, wtp, bias, out);
  } else {
    long n = (long)out_size;
    hipLaunchKernelGGL(naive_conv_kernel, dim3((unsigned)((n + 255) / 256)),
                       dim3(256), 0, stream, x, wgt, bias, out, n);
  }
}